// Round 1
// 1068.021 us; speedup vs baseline: 1.0098x; 1.0098x over previous
//
#include <hip/hip_runtime.h>
#include <hip/hip_bf16.h>

// Problem constants (fixed by the reference)
#define N_PTS 32768
#define K_CLU 8192
#define D_DIM 64
#define DECAYF 0.99f
#define OMDF   0.01f
#define EPSF   1e-5f

typedef _Float16 v8h __attribute__((ext_vector_type(8)));
typedef float    v4f __attribute__((ext_vector_type(4)));

#define AS1 __attribute__((address_space(1)))
#define AS3 __attribute__((address_space(3)))

// ---- workspace layout (bytes) ----
#define OFF_COUNTS 0                         // K uint32           = 32768 B
#define OFF_DW     (32768)                   // K*D fp32           = 2097152 B
#define OFF_NSUM   (OFF_DW + 2097152)        // 1 fp32 (+pad)      = 16 B
#define OFF_EHI    (OFF_NSUM + 16)           // K*D f16 (swizzled) = 1048576 B
#define OFF_ELO    (OFF_EHI + 1048576)       // K*D f16 (swizzled) = 1048576 B
#define OFF_E2     (OFF_ELO + 1048576)       // K fp32             = 32768 B

// ---------------------------------------------------------------------------
// prep: split embedding into f16 hi/lo (XOR-swizzled within each 128B row so
// fused can stage with linear global_load_lds and still read bank-uniform),
// row norms e2[k], and sum(ema_cs)
// swizzle: element (row, j) stored at row*64 + (((j>>3) ^ (row&7))<<3) + (j&7)
// ---------------------------------------------------------------------------
__global__ __launch_bounds__(256) void vq_prep(
    const float* __restrict__ emb, const float* __restrict__ ema_cs,
    _Float16* __restrict__ ehi, _Float16* __restrict__ elo,
    float* __restrict__ e2, float* __restrict__ nsum)
{
    const int wave = threadIdx.x >> 6;
    const int lane = threadIdx.x & 63;
    if (blockIdx.x < 2048) {
        const int row = blockIdx.x * 4 + wave;           // 0..8191
        float v = emb[(size_t)row * D_DIM + lane];
        _Float16 h = (_Float16)v;
        _Float16 l = (_Float16)(v - (float)h);
        const int sw = (lane & 7) | ((((lane >> 3) ^ (row & 7)) & 7) << 3);
        ehi[(size_t)row * D_DIM + sw] = h;
        elo[(size_t)row * D_DIM + sw] = l;
        float s = v * v;
        #pragma unroll
        for (int m = 1; m < 64; m <<= 1) s += __shfl_xor(s, m, 64);
        if (lane == 0) e2[row] = s;
    } else {
        const int t = (blockIdx.x - 2048) * 256 + threadIdx.x;  // 0..8191
        float v = ema_cs[t];
        #pragma unroll
        for (int m = 1; m < 64; m <<= 1) v += __shfl_xor(v, m, 64);
        if (lane == 0) atomicAdd(nsum, v);
    }
}

// ---------------------------------------------------------------------------
// fused main: 512 blocks x 256 threads, 2 blocks/CU.
//   - 4 waves x 16 points: f16x3-split MFMA distance argmin over K=8192
//   - DOUBLE-BUFFERED LDS staging via global_load_lds (linear copy of the
//     pre-swizzled rows): stage chunk t+1 while computing chunk t, ONE
//     __syncthreads per chunk (64 barriers instead of 128).
//   - two independent 3-MFMA accumulator chains per substep (was one 6-chain)
//   - paced nontemporal zero-stream of this block's 64 encoding rows
// ---------------------------------------------------------------------------
__global__ __launch_bounds__(256) void vq_fused(
    const float* __restrict__ x,
    const _Float16* __restrict__ ehi, const _Float16* __restrict__ elo,
    const float* __restrict__ e2,
    float* __restrict__ enc,
    unsigned int* __restrict__ counts,
    float* __restrict__ dw)
{
    __shared__ _Float16 sEhi[2][128 * 64];   // 2 x 16 KiB
    __shared__ _Float16 sElo[2][128 * 64];   // 2 x 16 KiB
    __shared__ float    sE2[2][128];         // 2 x 512 B

    const int bid  = blockIdx.x;             // 0..511
    const int tid  = threadIdx.x;
    const int wave = tid >> 6;
    const int lane = tid & 63;
    const int quad = lane >> 4;
    const int l15  = lane & 15;
    const int ptbase = bid * 64 + wave * 16;

    // Load this wave's 16-point X fragments once (A layout: A[m=lane&15][k=quad*8+j])
    v8h xh[2], xl[2];
    {
        const int pt = ptbase + l15;
        const float* xp = x + (size_t)pt * D_DIM + quad * 8;
        #pragma unroll
        for (int c = 0; c < 2; ++c) {
            float4 a = *(const float4*)(xp + c * 32);
            float4 b = *(const float4*)(xp + c * 32 + 4);
            float vv[8] = {a.x, a.y, a.z, a.w, b.x, b.y, b.z, b.w};
            v8h hh, ll;
            #pragma unroll
            for (int j = 0; j < 8; ++j) {
                _Float16 h = (_Float16)vv[j];
                hh[j] = h;
                ll[j] = (_Float16)(vv[j] - (float)h);
            }
            xh[c] = hh; xl[c] = ll;
        }
    }

    float best[4]; int bidx4[4];
    #pragma unroll
    for (int i = 0; i < 4; ++i) { best[i] = 3.4e38f; bidx4[i] = 0; }

    // zero-stream setup: block slice = 131072 float4 (2 MiB) = rows [bid*64,+64)
    v4f* enc4 = (v4f*)enc;
    const size_t zbase = (size_t)bid * 131072 + tid;
    const v4f zz = {0.f, 0.f, 0.f, 0.f};

    // -------- async staging of one 128-cluster chunk into buffer b ---------
    // ehi/elo rows are 128 B, pre-swizzled in global, so the copy is linear:
    // wave w stages bytes [w*4096, w*4096+4096) of each 16 KiB half.
    auto stage = [&](int b, int chunk) {
        const size_t gb = (size_t)chunk * 128 * 128;     // byte offset of chunk
        const char* gh = (const char*)ehi + gb;
        const char* gl = (const char*)elo + gb;
        char* lh = (char*)&sEhi[b][0];
        char* ll = (char*)&sElo[b][0];
        #pragma unroll
        for (int i = 0; i < 4; ++i) {
            const int off = wave * 4096 + i * 1024;      // wave-uniform LDS dest
            __builtin_amdgcn_global_load_lds(
                (const AS1 void*)(gh + off + lane * 16), (AS3 void*)(lh + off), 16, 0, 0);
            __builtin_amdgcn_global_load_lds(
                (const AS1 void*)(gl + off + lane * 16), (AS3 void*)(ll + off), 16, 0, 0);
        }
        if (wave == 0) {
            const char* ge = (const char*)(e2 + (size_t)chunk * 128);
            char* le = (char*)&sE2[b][0];
            #pragma unroll
            for (int i = 0; i < 2; ++i) {
                __builtin_amdgcn_global_load_lds(
                    (const AS1 void*)(ge + i * 256 + lane * 4), (AS3 void*)(le + i * 256), 4, 0, 0);
            }
        }
    };

    stage(0, 0);
    __syncthreads();   // drains vmcnt -> buffer 0 ready

    for (int chunk = 0; chunk < 64; ++chunk) {
        const int cur = chunk & 1;
        if (chunk + 1 < 64) stage(cur ^ 1, chunk + 1);   // async prefetch

        const int kbase = chunk * 128;
        const size_t zo = zbase + (size_t)chunk * 2048;
        #pragma unroll
        for (int sub = 0; sub < 8; ++sub) {
            // paced zero-stream: 1 nontemporal float4/thread per sub-step
            __builtin_nontemporal_store(zz, enc4 + zo + sub * 256);

            const int nl = sub * 16 + l15;
            const int ro = nl * 64;
            const int swz = (nl & 7) << 3;
            v8h bh0 = *(const v8h*)&sEhi[cur][ro + ((quad << 3) ^ swz)];
            v8h bh1 = *(const v8h*)&sEhi[cur][ro + (((4 + quad) << 3) ^ swz)];
            v8h bl0 = *(const v8h*)&sElo[cur][ro + ((quad << 3) ^ swz)];
            v8h bl1 = *(const v8h*)&sElo[cur][ro + (((4 + quad) << 3) ^ swz)];
            const float e2v = sE2[cur][nl];
            const int kidx = kbase + nl;
            // two independent 3-MFMA chains (halves exposed MFMA latency)
            v4f acc0 = {0.f, 0.f, 0.f, 0.f};
            v4f acc1 = {0.f, 0.f, 0.f, 0.f};
            acc0 = __builtin_amdgcn_mfma_f32_16x16x32_f16(xh[0], bh0, acc0, 0, 0, 0);
            acc1 = __builtin_amdgcn_mfma_f32_16x16x32_f16(xh[1], bh1, acc1, 0, 0, 0);
            acc0 = __builtin_amdgcn_mfma_f32_16x16x32_f16(xl[0], bh0, acc0, 0, 0, 0);
            acc1 = __builtin_amdgcn_mfma_f32_16x16x32_f16(xl[1], bh1, acc1, 0, 0, 0);
            acc0 = __builtin_amdgcn_mfma_f32_16x16x32_f16(xh[0], bl0, acc0, 0, 0, 0);
            acc1 = __builtin_amdgcn_mfma_f32_16x16x32_f16(xh[1], bl1, acc1, 0, 0, 0);
            #pragma unroll
            for (int r = 0; r < 4; ++r) {
                float dot = acc0[r] + acc1[r];
                float dist = fmaf(dot, -2.0f, e2v);   // x^2 omitted: row-constant
                if (dist < best[r]) { best[r] = dist; bidx4[r] = kidx; }
            }
        }
        __syncthreads();  // staged buffer ready; all reads of cur done; stores drained
    }

    // cross-lane argmin within each 16-lane group (cols), tie -> smaller index
    #pragma unroll
    for (int i = 0; i < 4; ++i) {
        #pragma unroll
        for (int m = 1; m < 16; m <<= 1) {
            float ov = __shfl_xor(best[i], m, 64);
            int   oi = __shfl_xor(bidx4[i], m, 64);
            if (ov < best[i] || (ov == best[i] && oi < bidx4[i])) { best[i] = ov; bidx4[i] = oi; }
        }
    }

    // barrier: __syncthreads drains vmcnt, so all zero-stores of this block's
    // rows are in memory before we overwrite the one-hot positions below.
    __syncthreads();

    // write ones + counts (l15==0 lane of quad q owns C rows q*4+r)
    if (l15 == 0) {
        #pragma unroll
        for (int r = 0; r < 4; ++r) {
            int p = ptbase + quad * 4 + r;
            enc[(size_t)p * K_CLU + bidx4[r]] = 1.0f;
            atomicAdd(&counts[bidx4[r]], 1u);
        }
    }

    // dw[k,:] += x[p,:] for each of this wave's 16 points (lane = d)
    #pragma unroll
    for (int j = 0; j < 16; ++j) {
        const int src = (j >> 2) * 16;         // l15==0 lane of owning quad
        const int r = j & 3;
        int k = __shfl(bidx4[r], src, 64);
        float val = x[(size_t)(ptbase + j) * D_DIM + lane];
        atomicAdd(&dw[(size_t)k * D_DIM + lane], val);
    }
}

// ---------------------------------------------------------------------------
// finalize: EMA outputs over K*D (2048 blocks); encodings fully written by fused
// ---------------------------------------------------------------------------
__global__ __launch_bounds__(256) void vq_finalize(
    const float* __restrict__ emb, const float* __restrict__ ema_w,
    const float* __restrict__ ema_cs,
    const unsigned int* __restrict__ counts, const float* __restrict__ dw,
    const float* __restrict__ nsum,
    float* __restrict__ out)
{
    const size_t ENC = (size_t)N_PTS * K_CLU;
    float* out_codebook = out + ENC;
    float* out_cs       = out_codebook + (size_t)K_CLU * D_DIM;
    float* out_ema      = out_cs + K_CLU;
    float* out_emb      = out_ema + (size_t)K_CLU * D_DIM;

    const int gid = blockIdx.x * 256 + threadIdx.x;   // 0..K*D-1
    const int k = gid >> 6, d = gid & 63;
    float dwv = dw[gid];
    float en  = DECAYF * ema_w[gid] + OMDF * dwv;
    float cnt = (float)counts[k];
    float cs_raw = DECAYF * ema_cs[k] + OMDF * cnt;
    // n = sum(cluster_size) = 0.99*sum(ema_cs) + 0.01*N  (sum(counts)==N exactly)
    float n  = DECAYF * nsum[0] + OMDF * (float)N_PTS;
    float cs = (cs_raw + EPSF) / (n + (float)K_CLU * EPSF) * n;
    out_codebook[gid] = emb[gid];
    out_ema[gid] = en;
    out_emb[gid] = en / cs;
    if (d == 0) out_cs[k] = cs;
}

extern "C" void kernel_launch(void* const* d_in, const int* in_sizes, int n_in,
                              void* d_out, int out_size, void* d_ws, size_t ws_size,
                              hipStream_t stream)
{
    const float* x      = (const float*)d_in[0];   // [N, D]
    const float* emb    = (const float*)d_in[1];   // [K, D]
    const float* ema_w  = (const float*)d_in[2];   // [K, D]
    const float* ema_cs = (const float*)d_in[3];   // [K]
    float* out = (float*)d_out;
    char* ws = (char*)d_ws;

    unsigned int* counts = (unsigned int*)(ws + OFF_COUNTS);
    float*        dw     = (float*)(ws + OFF_DW);
    float*        nsum   = (float*)(ws + OFF_NSUM);
    _Float16*     ehi    = (_Float16*)(ws + OFF_EHI);
    _Float16*     elo    = (_Float16*)(ws + OFF_ELO);
    float*        e2     = (float*)(ws + OFF_E2);

    // zero counts+dw+nsum (contiguous region); graph-capture-safe async memset
    hipMemsetAsync(ws + OFF_COUNTS, 0, (OFF_NSUM + 16) - OFF_COUNTS, stream);

    vq_prep<<<2080, 256, 0, stream>>>(emb, ema_cs, ehi, elo, e2, nsum);
    vq_fused<<<512, 256, 0, stream>>>(x, ehi, elo, e2, out, counts, dw);
    vq_finalize<<<2048, 256, 0, stream>>>(emb, ema_w, ema_cs, counts, dw, nsum, out);
}